// Round 5
// baseline (144139.697 us; speedup 1.0000x reference)
//
#include <hip/hip_runtime.h>
#include <math.h>

// Problem constants
#define HH    1028        // real hidden size
#define TT    16384       // timesteps
#define UP    1056        // padded hidden (= 16*66 = 8*132)
#define HSU   1056        // (val,tag) u64 pairs per ring row
#define HS    1056        // floats per h2 history row
#define NWG0  66          // layer-0 WGs, 16 units each, 1 wave/unit
#define NWG1  132         // layer-1 WGs, 8 units each, 1 wave/unit + 8 stage waves
#define NWGT  (NWG0 + NWG1)
#define R0    1024        // h1 ring depth
#define R0M   (R0 - 1)
#define R1M   15          // h2 ring depth 16

typedef unsigned long long u64;
typedef unsigned int uint4v __attribute__((ext_vector_type(4)));

// ---------- MALL-coherent primitives ----------
__device__ __forceinline__ u64 ld_u64(const u64* p) {
    return __hip_atomic_load(p, __ATOMIC_RELAXED, __HIP_MEMORY_SCOPE_AGENT);
}
__device__ __forceinline__ void st_u64(u64* p, u64 v) {
    __hip_atomic_store(p, v, __ATOMIC_RELAXED, __HIP_MEMORY_SCOPE_AGENT);
}
__device__ __forceinline__ unsigned ld_u32(const unsigned* p) {
    return __hip_atomic_load(p, __ATOMIC_RELAXED, __HIP_MEMORY_SCOPE_AGENT);
}
__device__ __forceinline__ void st_u32(unsigned* p, unsigned v) {
    __hip_atomic_store(p, v, __ATOMIC_RELAXED, __HIP_MEMORY_SCOPE_AGENT);
}
// LDS tagged-handshake primitives (ds ops, not reg-cached)
__device__ __forceinline__ u64 ld_lds_u64(const u64* p) {
    return __hip_atomic_load(p, __ATOMIC_RELAXED, __HIP_MEMORY_SCOPE_WORKGROUP);
}
__device__ __forceinline__ void st_lds_u64(u64* p, u64 v) {
    __hip_atomic_store(p, v, __ATOMIC_RELAXED, __HIP_MEMORY_SCOPE_WORKGROUP);
}
__device__ __forceinline__ float sigmf(float x) { return 1.0f / (1.0f + expf(-x)); }
__device__ __forceinline__ u64 pack(unsigned tag, float v) {
    return ((u64)tag << 32) | (u64)__float_as_uint(v);
}

// 16B coherent poll load: two (val,tag) pairs per request (r4-verified win).
#define POLL16(dst, ptr) \
    asm volatile("global_load_dwordx4 %0, %1, off sc0 sc1" : "=v"(dst) : "v"(ptr))

// Stage 66 pairs [base, base+66) into LDS via 33 x 16B polls (lanes 0-32).
__device__ __forceinline__ void stage66w(const u64* __restrict__ src, float* __restrict__ lds,
                                         int base, int lane, unsigned want, long long& budget) {
    const u64* p0 = src + base + 2 * lane;
    bool d0 = (lane >= 33);
    uint4v r0 = {0, 0, 0, 0};
    int spin = 2;
    for (;;) {
        if (!d0) POLL16(r0, p0);
        asm volatile("s_waitcnt vmcnt(0)" ::: "memory");
        __builtin_amdgcn_sched_barrier(0);
        if (!d0 && r0[1] == want && r0[3] == want) {
            *(float2*)&lds[base + 2 * lane] =
                make_float2(__uint_as_float(r0[0]), __uint_as_float(r0[2]));
            d0 = true;
        }
        if (__all(d0)) break;
        if (--budget < 0) break;          // hang safety valve
        if (spin > 0) { --spin; continue; }
        __builtin_amdgcn_s_sleep(1);
    }
}

// Stage 264 pairs [base, base+264) via 132 x 16B polls.
__device__ __forceinline__ void stage264w(const u64* __restrict__ src, float* __restrict__ lds,
                                          int base, int lane, unsigned want, long long& budget) {
    const u64* p0 = src + base + 2 * lane;
    const u64* p1 = src + base + 2 * (64 + lane);
    const u64* p2 = src + base + 2 * (128 + lane);  // lanes 0-3
    bool d0 = false, d1 = false, d2 = (lane >= 4);
    uint4v r0 = {0, 0, 0, 0}, r1 = {0, 0, 0, 0}, r2 = {0, 0, 0, 0};
    int spin = 2;
    for (;;) {
        if (!d0) POLL16(r0, p0);
        if (!d1) POLL16(r1, p1);
        if (!d2) POLL16(r2, p2);
        asm volatile("s_waitcnt vmcnt(0)" ::: "memory");
        __builtin_amdgcn_sched_barrier(0);
        if (!d0 && r0[1] == want && r0[3] == want) {
            *(float2*)&lds[base + 2 * lane] =
                make_float2(__uint_as_float(r0[0]), __uint_as_float(r0[2]));
            d0 = true;
        }
        if (!d1 && r1[1] == want && r1[3] == want) {
            *(float2*)&lds[base + 2 * (64 + lane)] =
                make_float2(__uint_as_float(r1[0]), __uint_as_float(r1[2]));
            d1 = true;
        }
        if (!d2 && r2[1] == want && r2[3] == want) {
            *(float2*)&lds[base + 2 * (128 + lane)] =
                make_float2(__uint_as_float(r2[0]), __uint_as_float(r2[2]));
            d2 = true;
        }
        if (__all(d0 & d1 & d2)) break;
        if (--budget < 0) break;
        if (spin > 0) { --spin; continue; }
        __builtin_amdgcn_s_sleep(1);
    }
}

// ---------- fused 2-layer LSTM recurrence (wave = unit) ----------
__global__ __launch_bounds__(1024, 4) void wn_fused(
    const float* __restrict__ x,
    const float* __restrict__ w_ih0, const float* __restrict__ w_hh0,
    const float* __restrict__ b_ih0, const float* __restrict__ b_hh0,
    const float* __restrict__ w_ih1, const float* __restrict__ w_hh1,
    const float* __restrict__ b_ih1, const float* __restrict__ b_hh1,
    u64* __restrict__ ring0,                  // [R0][HSU] (val,tag) of h1
    u64* __restrict__ ring1,                  // [16][HSU] (val,tag) of h2
    float* __restrict__ h2hist,               // [TT][HS] plain h2 for projection
    unsigned* __restrict__ l1prog)            // L1 WG0 progress (poison-tolerant)
{
    __shared__ float smem[4 * UP + 64];
    const int tid  = threadIdx.x;
    const int lane = tid & 63;
    const int w    = tid >> 6;                // wave 0..15

    for (int i = tid; i < 4 * UP + 64; i += 1024) smem[i] = 0.0f;

    if (blockIdx.x < NWG0) {
        // ===== layer 0: 16 units/WG, wave w owns unit wg*16+w; 64 k-lanes/unit =====
        float* hbuf = smem;                   // [2][UP] staged h1
        u64*   pbuf = (u64*)(smem + 4 * UP);  // [16] tagged unit outputs
        const int wg   = blockIdx.x;
        const int u    = wg * 16 + w;
        const bool real = (u < HH);

        // weights: all 4 gates of unit u, k-slice {lane*4+m*256 | m<4} + tail
        float wv[4][4][4];                    // [gate][m][q]
        float wt[4][4];                       // tail k=1024+lane*4 (lanes 0-7)
        float wx[4], bsg[4];
#pragma unroll
        for (int g = 0; g < 4; ++g) {
            const int wr = g * HH + (real ? u : 0);
#pragma unroll
            for (int m = 0; m < 4; ++m) {
                const int j = lane * 4 + m * 256;   // ≤1023, always < HH
#pragma unroll
                for (int q = 0; q < 4; ++q)
                    wv[g][m][q] = real ? w_hh0[(size_t)wr * HH + j + q] : 0.0f;
            }
#pragma unroll
            for (int q = 0; q < 4; ++q) {
                const int j = 1024 + lane * 4 + q;
                wt[g][q] = (real && lane < 8 && j < HH) ? w_hh0[(size_t)wr * HH + j] : 0.0f;
            }
            wx[g]  = real ? w_ih0[wr] : 0.0f;
            bsg[g] = real ? (b_ih0[wr] + b_hh0[wr]) : 0.0f;
        }
#pragma unroll
        for (int g = 0; g < 4; ++g)
#pragma unroll
            for (int m = 0; m < 4; ++m)
#pragma unroll
                for (int q = 0; q < 4; ++q) asm volatile("" : "+v"(wv[g][m][q]));
        __syncthreads();

        long long budget = 20000000LL;
        float c_reg = 0.0f;                   // replicated across lanes
        for (int t = 0; t < TT; ++t) {
            const float xt = x[t];
            const float* hb = hbuf + (t & 1) * UP;
            float acc[4] = {0.f, 0.f, 0.f, 0.f};
#pragma unroll
            for (int m = 0; m < 4; ++m) {
                const float4 hv4 = *(const float4*)&hb[lane * 4 + m * 256];
#pragma unroll
                for (int g = 0; g < 4; ++g) {
                    acc[g] = fmaf(wv[g][m][0], hv4.x, acc[g]);
                    acc[g] = fmaf(wv[g][m][1], hv4.y, acc[g]);
                    acc[g] = fmaf(wv[g][m][2], hv4.z, acc[g]);
                    acc[g] = fmaf(wv[g][m][3], hv4.w, acc[g]);
                }
            }
            if (lane < 8) {
                const float4 hv4 = *(const float4*)&hb[1024 + lane * 4];
#pragma unroll
                for (int g = 0; g < 4; ++g) {
                    acc[g] = fmaf(wt[g][0], hv4.x, acc[g]);
                    acc[g] = fmaf(wt[g][1], hv4.y, acc[g]);
                    acc[g] = fmaf(wt[g][2], hv4.z, acc[g]);
                    acc[g] = fmaf(wt[g][3], hv4.w, acc[g]);
                }
            }
            // 64-lane butterflies: every lane ends with all 4 gate sums
#pragma unroll
            for (int off = 1; off < 64; off <<= 1) {
#pragma unroll
                for (int g = 0; g < 4; ++g) acc[g] += __shfl_xor(acc[g], off);
            }
#pragma unroll
            for (int g = 0; g < 4; ++g) acc[g] = fmaf(xt, wx[g], acc[g]) + bsg[g];
            // in-wave epilogue (replicated)
            const float iv = sigmf(acc[0]), fv = sigmf(acc[1]);
            const float gv = tanhf(acc[2]), ov = sigmf(acc[3]);
            c_reg = fv * c_reg + iv * gv;
            float hv = ov * tanhf(c_reg);
            if (!real) hv = 0.0f;
            if (lane == 0) st_lds_u64(&pbuf[w], pack((unsigned)(t + 1), hv));

            if (w == 0) {
                // gather 16 tagged outputs, publish as ONE coalesced 128B burst
                const unsigned want = (unsigned)(t + 1);
                u64 pv = 0; bool d = (lane >= 16);
                for (;;) {
                    if (!d) { u64 v2 = ld_lds_u64(&pbuf[lane]);
                              if ((unsigned)(v2 >> 32) == want) { pv = v2; d = true; } }
                    if (__all(d)) break;
                    if (--budget < 0) break;
                }
                if (lane < 16)
                    st_u64(ring0 + (size_t)(t & R0M) * HSU + wg * 16 + lane, pv);
            } else if (w == 1 && lane == 0 && t > 0 && (t & 255) == 0) {
                for (;;) {                    // ring backpressure: never lap L1
                    unsigned p = ld_u32(l1prog);
                    if ((int)t - (int)p < R0 - 256) break;
                    if (--budget < 0) break;
                    __builtin_amdgcn_s_sleep(32);
                }
            }
            // stage h1[t] (tag t+1) for next step; parity keeps halves disjoint
            if (t + 1 < TT)
                stage66w(ring0 + (size_t)(t & R0M) * HSU, hbuf + ((t + 1) & 1) * UP,
                         w * 66, lane, (unsigned)(t + 1), budget);
            __syncthreads();                   // only barrier per step
        }
    } else {
        // ===== layer 1: 8 units/WG. waves 0-7 = units; waves 8-15 = staging =====
        float* abuf = smem;                   // [2][UP] h1[t]
        float* bbuf = smem + 2 * UP;          // [2][UP] h2[t-1]
        u64*   pbuf = (u64*)(smem + 4 * UP);  // [8]
        const int wg   = blockIdx.x - NWG0;   // 0..131
        const bool comp = (w < 8);
        const int u    = wg * 8 + (comp ? w : 0);
        const bool real = comp && (u < HH);

        float wiv[4][4][4], whv[4][4][4];     // [gate][m][q]
        float wti[4][4], wth[4][4], bsg[4];
        if (comp) {
#pragma unroll
            for (int g = 0; g < 4; ++g) {
                const int wr = g * HH + (real ? u : 0);
#pragma unroll
                for (int m = 0; m < 4; ++m) {
                    const int j = lane * 4 + m * 256;
#pragma unroll
                    for (int q = 0; q < 4; ++q) {
                        wiv[g][m][q] = real ? w_ih1[(size_t)wr * HH + j + q] : 0.0f;
                        whv[g][m][q] = real ? w_hh1[(size_t)wr * HH + j + q] : 0.0f;
                    }
                }
#pragma unroll
                for (int q = 0; q < 4; ++q) {
                    const int j = 1024 + lane * 4 + q;
                    const bool inb = real && lane < 8 && j < HH;
                    wti[g][q] = inb ? w_ih1[(size_t)wr * HH + j] : 0.0f;
                    wth[g][q] = inb ? w_hh1[(size_t)wr * HH + j] : 0.0f;
                }
                bsg[g] = real ? (b_ih1[wr] + b_hh1[wr]) : 0.0f;
            }
#pragma unroll
            for (int g = 0; g < 4; ++g)
#pragma unroll
                for (int m = 0; m < 4; ++m)
#pragma unroll
                    for (int q = 0; q < 4; ++q) {
                        asm volatile("" : "+v"(wiv[g][m][q]));
                        asm volatile("" : "+v"(whv[g][m][q]));
                    }
        }
        long long budget = 20000000LL;
        // prologue: stage h1[0] (tag 1) into abuf half 0
        if (w >= 12)
            stage264w(ring0, abuf, (w - 12) * 264, lane, 1u, budget);
        __syncthreads();

        float c_reg = 0.0f;
        for (int t = 0; t < TT; ++t) {
            if (comp) {
                const float* ab = abuf + (t & 1) * UP;
                const float* bb = bbuf + (t & 1) * UP;
                float acc[4] = {0.f, 0.f, 0.f, 0.f};
#pragma unroll
                for (int m = 0; m < 4; ++m) {
                    const float4 ha = *(const float4*)&ab[lane * 4 + m * 256];
                    const float4 hc = *(const float4*)&bb[lane * 4 + m * 256];
#pragma unroll
                    for (int g = 0; g < 4; ++g) {
                        acc[g] = fmaf(wiv[g][m][0], ha.x, acc[g]);
                        acc[g] = fmaf(wiv[g][m][1], ha.y, acc[g]);
                        acc[g] = fmaf(wiv[g][m][2], ha.z, acc[g]);
                        acc[g] = fmaf(wiv[g][m][3], ha.w, acc[g]);
                        acc[g] = fmaf(whv[g][m][0], hc.x, acc[g]);
                        acc[g] = fmaf(whv[g][m][1], hc.y, acc[g]);
                        acc[g] = fmaf(whv[g][m][2], hc.z, acc[g]);
                        acc[g] = fmaf(whv[g][m][3], hc.w, acc[g]);
                    }
                }
                if (lane < 8) {
                    const float4 ha = *(const float4*)&ab[1024 + lane * 4];
                    const float4 hc = *(const float4*)&bb[1024 + lane * 4];
#pragma unroll
                    for (int g = 0; g < 4; ++g) {
                        acc[g] = fmaf(wti[g][0], ha.x, acc[g]);
                        acc[g] = fmaf(wti[g][1], ha.y, acc[g]);
                        acc[g] = fmaf(wti[g][2], ha.z, acc[g]);
                        acc[g] = fmaf(wti[g][3], ha.w, acc[g]);
                        acc[g] = fmaf(wth[g][0], hc.x, acc[g]);
                        acc[g] = fmaf(wth[g][1], hc.y, acc[g]);
                        acc[g] = fmaf(wth[g][2], hc.z, acc[g]);
                        acc[g] = fmaf(wth[g][3], hc.w, acc[g]);
                    }
                }
#pragma unroll
                for (int off = 1; off < 64; off <<= 1) {
#pragma unroll
                    for (int g = 0; g < 4; ++g) acc[g] += __shfl_xor(acc[g], off);
                }
#pragma unroll
                for (int g = 0; g < 4; ++g) acc[g] += bsg[g];
                const float iv = sigmf(acc[0]), fv = sigmf(acc[1]);
                const float gv = tanhf(acc[2]), ov = sigmf(acc[3]);
                c_reg = fv * c_reg + iv * gv;
                float hv = ov * tanhf(c_reg);
                if (!real) hv = 0.0f;
                if (lane == 0) st_lds_u64(&pbuf[w], pack((unsigned)(t + 1), hv));

                if (w == 0) {
                    // gather 8 outputs, one 64B burst + h2hist write
                    const unsigned want = (unsigned)(t + 1);
                    u64 pv = 0; bool d = (lane >= 8);
                    for (;;) {
                        if (!d) { u64 v2 = ld_lds_u64(&pbuf[lane]);
                                  if ((unsigned)(v2 >> 32) == want) { pv = v2; d = true; } }
                        if (__all(d)) break;
                        if (--budget < 0) break;
                    }
                    if (lane < 8) {
                        st_u64(ring1 + (size_t)(t & R1M) * HSU + wg * 8 + lane, pv);
                        h2hist[(size_t)t * HS + wg * 8 + lane] = __uint_as_float((unsigned)pv);
                    }
                } else if (wg == 0 && w == 1 && lane == 0 && (t & 255) == 255) {
                    st_u32(l1prog, (unsigned)(t + 1));    // backpressure progress
                }
            } else if (w < 12) {
                // stage h2[t] (tag t+1) for step t+1 — the critical self-loop
                if (t + 1 < TT)
                    stage264w(ring1 + (size_t)(t & R1M) * HSU, bbuf + ((t + 1) & 1) * UP,
                              (w - 8) * 264, lane, (unsigned)(t + 1), budget);
            } else {
                // stage h1[t+1] (tag t+2) for step t+1 — L0 runs ahead, fast
                if (t + 1 < TT)
                    stage264w(ring0 + (size_t)((t + 1) & R0M) * HSU, abuf + ((t + 1) & 1) * UP,
                              (w - 12) * 264, lane, (unsigned)(t + 2), budget);
            }
            __syncthreads();                   // only barrier per step
        }
    }
}

// ---------- final projection: out[t] = lin_w . h2[t] + lin_b ----------
__global__ __launch_bounds__(256) void wn_proj(
    const float* __restrict__ h2,
    const float* __restrict__ lin_w,
    const float* __restrict__ lin_b,
    float* __restrict__ out)
{
    const int lane = threadIdx.x & 63;
    const int wv   = threadIdx.x >> 6;
    const int t    = blockIdx.x * 4 + wv;
    const float* hp = h2 + (size_t)t * HS;
    float acc = 0.0f;
#pragma unroll
    for (int m = 0; m < 4; ++m) {
        const int j = lane * 4 + m * 256;        // covers [0,1024)
        const float4 h4 = *(const float4*)(hp + j);
        const float4 w4 = *(const float4*)(lin_w + j);
        acc += h4.x * w4.x + h4.y * w4.y + h4.z * w4.z + h4.w * w4.w;
    }
    if (lane == 0) {
#pragma unroll
        for (int j = 1024; j < HH; ++j) acc += hp[j] * lin_w[j];
    }
#pragma unroll
    for (int off = 1; off < 64; off <<= 1) acc += __shfl_xor(acc, off);
    if (lane == 0) out[t] = acc + lin_b[0];
}

extern "C" void kernel_launch(void* const* d_in, const int* in_sizes, int n_in,
                              void* d_out, int out_size, void* d_ws, size_t ws_size,
                              hipStream_t stream) {
    const float* x     = (const float*)d_in[0];
    const float* w_ih0 = (const float*)d_in[1];
    const float* w_hh0 = (const float*)d_in[2];
    const float* b_ih0 = (const float*)d_in[3];
    const float* b_hh0 = (const float*)d_in[4];
    const float* w_ih1 = (const float*)d_in[5];
    const float* w_hh1 = (const float*)d_in[6];
    const float* b_ih1 = (const float*)d_in[7];
    const float* b_hh1 = (const float*)d_in[8];
    const float* lin_w = (const float*)d_in[9];
    const float* lin_b = (const float*)d_in[10];
    float* out = (float*)d_out;

    char* ws = (char*)d_ws;
    const size_t R0B = (size_t)R0 * HSU * 8;        //  8,650,752
    const size_t R1B = (size_t)16 * HSU * 8;        //    135,168
    const size_t H2B = (size_t)TT * HS * 4;         // 69,206,016
    u64* ring0 = (u64*)(ws);
    u64* ring1 = (u64*)(ws + R0B);
    float* h2hist = (float*)(ws + R0B + R1B);
    unsigned* l1prog = (unsigned*)(ws + R0B + R1B + H2B);
    // No init kernel: 0xAA poison never matches any tag (1..16384), and the
    // poisoned l1prog reads as negative -> L0 throttles until L1 publishes.

    wn_fused<<<NWGT, 1024, 0, stream>>>(x, w_ih0, w_hh0, b_ih0, b_hh0,
                                        w_ih1, w_hh1, b_ih1, b_hh1,
                                        ring0, ring1, h2hist, l1prog);
    wn_proj<<<TT / 4, 256, 0, stream>>>(h2hist, lin_w, lin_b, out);
}

// Round 6
// 44861.267 us; speedup vs baseline: 3.2130x; 3.2130x over previous
//
#include <hip/hip_runtime.h>
#include <math.h>

// Problem constants
#define HH    1028        // real hidden size
#define TT    16384       // timesteps
#define UP    1056        // padded hidden (= 16*66 = 8*132)
#define HSU   1056        // (val,tag) u64 pairs per ring row
#define HS    1056        // floats per h2 history row
#define NWG0  66          // layer-0 WGs, 16 units each
#define NWG1  132         // layer-1 WGs, 8 units each
#define NWGT  (NWG0 + NWG1)
#define R0    1024        // h1 ring depth
#define R0M   (R0 - 1)
#define R1M   15          // h2 ring depth 16

typedef unsigned long long u64;
typedef unsigned int uint4v __attribute__((ext_vector_type(4)));

// ---------- MALL-coherent primitives ----------
__device__ __forceinline__ u64 ld_u64(const u64* p) {
    return __hip_atomic_load(p, __ATOMIC_RELAXED, __HIP_MEMORY_SCOPE_AGENT);
}
__device__ __forceinline__ void st_u64(u64* p, u64 v) {
    __hip_atomic_store(p, v, __ATOMIC_RELAXED, __HIP_MEMORY_SCOPE_AGENT);
}
__device__ __forceinline__ unsigned ld_u32(const unsigned* p) {
    return __hip_atomic_load(p, __ATOMIC_RELAXED, __HIP_MEMORY_SCOPE_AGENT);
}
__device__ __forceinline__ void st_u32(unsigned* p, unsigned v) {
    __hip_atomic_store(p, v, __ATOMIC_RELAXED, __HIP_MEMORY_SCOPE_AGENT);
}
__device__ __forceinline__ float sigmf(float x) { return 1.0f / (1.0f + expf(-x)); }
__device__ __forceinline__ u64 pack(unsigned tag, float v) {
    return ((u64)tag << 32) | (u64)__float_as_uint(v);
}

// 16B coherent poll load: two (val,tag) pairs per request (r4-verified win).
#define POLL16(dst, ptr) \
    asm volatile("global_load_dwordx4 %0, %1, off sc0 sc1" : "=v"(dst) : "v"(ptr))

// Stage 132 (val,tag) pairs [base, base+132) into LDS via 66 x 16B polls.
__device__ __forceinline__ void stage132w(const u64* __restrict__ src, float* __restrict__ lds,
                                          int base, int lane, unsigned want, long long& budget) {
    const u64* p0 = src + base + 2 * lane;          // chunk lane      (all 64)
    const u64* p1 = src + base + 2 * (64 + lane);   // chunk 64+lane   (lanes 0-1)
    bool d0 = false, d1 = (lane >= 2);
    uint4v r0 = {0, 0, 0, 0}, r1 = {0, 0, 0, 0};
    int spin = 2;
    for (;;) {
        if (!d0) POLL16(r0, p0);
        if (!d1) POLL16(r1, p1);
        asm volatile("s_waitcnt vmcnt(0)" ::: "memory");
        __builtin_amdgcn_sched_barrier(0);          // no reg-only hoist past waitcnt
        if (!d0 && r0[1] == want && r0[3] == want) {
            *(float2*)&lds[base + 2 * lane] =
                make_float2(__uint_as_float(r0[0]), __uint_as_float(r0[2]));
            d0 = true;
        }
        if (!d1 && r1[1] == want && r1[3] == want) {
            *(float2*)&lds[base + 2 * (64 + lane)] =
                make_float2(__uint_as_float(r1[0]), __uint_as_float(r1[2]));
            d1 = true;
        }
        if (__all(d0 & d1)) break;
        if (--budget < 0) break;          // hang safety valve
        if (spin > 0) { --spin; continue; }
        __builtin_amdgcn_s_sleep(1);
    }
}

// Stage 264 pairs [base, base+264) via 132 x 16B polls.
__device__ __forceinline__ void stage264w(const u64* __restrict__ src, float* __restrict__ lds,
                                          int base, int lane, unsigned want, long long& budget) {
    const u64* p0 = src + base + 2 * lane;
    const u64* p1 = src + base + 2 * (64 + lane);
    const u64* p2 = src + base + 2 * (128 + lane);  // lanes 0-3
    bool d0 = false, d1 = false, d2 = (lane >= 4);
    uint4v r0 = {0, 0, 0, 0}, r1 = {0, 0, 0, 0}, r2 = {0, 0, 0, 0};
    int spin = 2;
    for (;;) {
        if (!d0) POLL16(r0, p0);
        if (!d1) POLL16(r1, p1);
        if (!d2) POLL16(r2, p2);
        asm volatile("s_waitcnt vmcnt(0)" ::: "memory");
        __builtin_amdgcn_sched_barrier(0);
        if (!d0 && r0[1] == want && r0[3] == want) {
            *(float2*)&lds[base + 2 * lane] =
                make_float2(__uint_as_float(r0[0]), __uint_as_float(r0[2]));
            d0 = true;
        }
        if (!d1 && r1[1] == want && r1[3] == want) {
            *(float2*)&lds[base + 2 * (64 + lane)] =
                make_float2(__uint_as_float(r1[0]), __uint_as_float(r1[2]));
            d1 = true;
        }
        if (!d2 && r2[1] == want && r2[3] == want) {
            *(float2*)&lds[base + 2 * (128 + lane)] =
                make_float2(__uint_as_float(r2[0]), __uint_as_float(r2[2]));
            d2 = true;
        }
        if (__all(d0 & d1 & d2)) break;
        if (--budget < 0) break;
        if (spin > 0) { --spin; continue; }
        __builtin_amdgcn_s_sleep(1);
    }
}

// ---------- fused 2-layer LSTM recurrence ----------
// Structure = r4 (verified 40.7ms): phase P (epilogue+publish || staging) /
// barrier A / compute / barrier B.  Compute rows remapped to (unit, gate-PAIR):
// each lane loads its h-slice once and feeds 2 gate accumulators -> LDS-read
// instruction count per WG-step roughly halves.  gbuf layout unchanged.
__global__ __launch_bounds__(1024, 4) void wn_fused(
    const float* __restrict__ x,
    const float* __restrict__ w_ih0, const float* __restrict__ w_hh0,
    const float* __restrict__ b_ih0, const float* __restrict__ b_hh0,
    const float* __restrict__ w_ih1, const float* __restrict__ w_hh1,
    const float* __restrict__ b_ih1, const float* __restrict__ b_hh1,
    u64* __restrict__ ring0,                  // [R0][HSU] (val,tag) of h1
    u64* __restrict__ ring1,                  // [16][HSU] (val,tag) of h2
    float* __restrict__ h2hist,               // [TT][HS] plain h2 for projection
    unsigned* __restrict__ l1prog)            // L1 WG0 progress (poison-tolerant)
{
    __shared__ float smem[4 * UP + 128];
    const int tid  = threadIdx.x;
    const int lane = tid & 63;
    const int w    = tid >> 6;                // wave 0..15

    for (int i = tid; i < 4 * UP + 128; i += 1024) smem[i] = 0.0f;

    if (blockIdx.x < NWG0) {
        // ===== layer 0: rows = 16 units x 2 gate-pairs, 32 lanes/row =====
        float* hbuf = smem;                   // [2][UP] staged h1
        float* gbuf = smem + 2 * UP;          // [2][64] gate pre-activations (g*16+du)
        const int wg   = blockIdx.x;
        const int r    = tid >> 5;            // 0..31
        const int k0   = tid & 31;
        const int du   = r & 15;              // unit within WG
        const int gp   = r >> 4;              // gate-pair: 0=(i,f), 1=(g,o)
        const int u    = wg * 16 + du;
        const bool real = (u < HH);

        float wv[2][8][4];                    // [g2][m][q], j = k0*4 + m*128
        float wt[2][4];                       // tail j = 1024+k0*4 (k0<8)
        float wx2[2], bs2[2];
#pragma unroll
        for (int g2 = 0; g2 < 2; ++g2) {
            const int wr = (gp * 2 + g2) * HH + (real ? u : 0);
#pragma unroll
            for (int m = 0; m < 8; ++m) {
                const int j = k0 * 4 + m * 128;     // <= 1023, always < HH
#pragma unroll
                for (int q = 0; q < 4; ++q)
                    wv[g2][m][q] = real ? w_hh0[(size_t)wr * HH + j + q] : 0.0f;
            }
#pragma unroll
            for (int q = 0; q < 4; ++q) {
                const int j = 1024 + k0 * 4 + q;
                wt[g2][q] = (real && k0 < 8 && j < HH) ? w_hh0[(size_t)wr * HH + j] : 0.0f;
            }
            wx2[g2] = real ? w_ih0[wr] : 0.0f;
            bs2[g2] = real ? (b_ih0[wr] + b_hh0[wr]) : 0.0f;
        }
#pragma unroll
        for (int g2 = 0; g2 < 2; ++g2)
#pragma unroll
            for (int m = 0; m < 8; ++m)
#pragma unroll
                for (int q = 0; q < 4; ++q) asm volatile("" : "+v"(wv[g2][m][q]));
        __syncthreads();

        long long budget = 20000000LL;
        float c_reg = 0.0f;                   // lives in wave0 lanes<16 (epilogue)
        for (int t = 0; t < TT; ++t) {
            // ---- phase P: epilogue+publish(t-1) [wave0] || stage h1(t-1) [w4-11] ----
            if (t > 0) {
                if (w == 0) {
                    const float* gl = gbuf + ((t - 1) & 1) * 64;
                    if (lane < 16) {
                        const float gi = gl[lane], gf = gl[16 + lane];
                        const float gg = gl[32 + lane], go = gl[48 + lane];
                        const float iv = sigmf(gi), fv = sigmf(gf), gv = tanhf(gg), ov = sigmf(go);
                        c_reg = fv * c_reg + iv * gv;
                        float hv = ov * tanhf(c_reg);
                        if (wg * 16 + lane >= HH) hv = 0.0f;
                        st_u64(ring0 + (size_t)((t - 1) & R0M) * HSU + wg * 16 + lane,
                               pack((unsigned)t, hv));      // coalesced 128B burst
                    }
                } else if (w >= 4 && w < 12) {
                    stage132w(ring0 + (size_t)((t - 1) & R0M) * HSU, hbuf + (t & 1) * UP,
                              (w - 4) * 132, lane, (unsigned)t, budget);
                } else if (w == 1 && lane == 0 && (t & 255) == 0) {
                    for (;;) {                 // ring backpressure: never lap L1
                        unsigned p = ld_u32(l1prog);
                        if ((int)t - (int)p < R0 - 256) break;
                        if (--budget < 0) break;
                        __builtin_amdgcn_s_sleep(32);
                    }
                }
            }
            __syncthreads();                   // A: stage visible
            const float* hb = hbuf + (t & 1) * UP;
            float a0 = 0.0f, a1 = 0.0f;
#pragma unroll
            for (int m = 0; m < 8; ++m) {
                const float4 hv4 = *(const float4*)&hb[k0 * 4 + m * 128];
                a0 = fmaf(wv[0][m][0], hv4.x, a0);
                a0 = fmaf(wv[0][m][1], hv4.y, a0);
                a0 = fmaf(wv[0][m][2], hv4.z, a0);
                a0 = fmaf(wv[0][m][3], hv4.w, a0);
                a1 = fmaf(wv[1][m][0], hv4.x, a1);
                a1 = fmaf(wv[1][m][1], hv4.y, a1);
                a1 = fmaf(wv[1][m][2], hv4.z, a1);
                a1 = fmaf(wv[1][m][3], hv4.w, a1);
            }
            if (k0 < 8) {
                const float4 hv4 = *(const float4*)&hb[1024 + k0 * 4];
                a0 = fmaf(wt[0][0], hv4.x, a0);
                a0 = fmaf(wt[0][1], hv4.y, a0);
                a0 = fmaf(wt[0][2], hv4.z, a0);
                a0 = fmaf(wt[0][3], hv4.w, a0);
                a1 = fmaf(wt[1][0], hv4.x, a1);
                a1 = fmaf(wt[1][1], hv4.y, a1);
                a1 = fmaf(wt[1][2], hv4.z, a1);
                a1 = fmaf(wt[1][3], hv4.w, a1);
            }
            // 32-lane butterflies (xor<32 stays within the half-wave row)
#pragma unroll
            for (int off = 1; off < 32; off <<= 1) {
                a0 += __shfl_xor(a0, off);
                a1 += __shfl_xor(a1, off);
            }
            if (k0 == 0) {
                const float xt = x[t];
                float* gw = gbuf + (t & 1) * 64;
                gw[(gp * 2 + 0) * 16 + du] = fmaf(xt, wx2[0], a0) + bs2[0];
                gw[(gp * 2 + 1) * 16 + du] = fmaf(xt, wx2[1], a1) + bs2[1];
            }
            __syncthreads();                   // B: gates visible for next P
        }
        // final epilogue+publish for t = TT-1
        if (w == 0 && lane < 16) {
            const float* gl = gbuf + ((TT - 1) & 1) * 64;
            const float gi = gl[lane], gf = gl[16 + lane];
            const float gg = gl[32 + lane], go = gl[48 + lane];
            const float iv = sigmf(gi), fv = sigmf(gf), gv = tanhf(gg), ov = sigmf(go);
            c_reg = fv * c_reg + iv * gv;
            float hv = ov * tanhf(c_reg);
            if (wg * 16 + lane >= HH) hv = 0.0f;
            st_u64(ring0 + (size_t)((TT - 1) & R0M) * HSU + wg * 16 + lane,
                   pack((unsigned)TT, hv));
        }
    } else {
        // ===== layer 1: rows = 8 units x 2 gate-pairs, 64 lanes/row (row = wave) =====
        float* abuf = smem;                   // [2][UP] h1[t]
        float* bbuf = smem + 2 * UP;          // [2][UP] h2[t-1]
        float* gbuf = smem + 4 * UP;          // [2][32] (g*8+du)
        const int wg   = blockIdx.x - NWG0;   // 0..131
        const int du   = w & 7;               // unit within WG
        const int gp   = w >> 3;              // gate-pair
        const int u    = wg * 8 + du;
        const bool real = (u < HH);

        float wiv[2][4][4], whv[2][4][4];     // [g2][m][q], j = lane*4 + m*256
        float wti[2][4], wth[2][4], bs2[2];
#pragma unroll
        for (int g2 = 0; g2 < 2; ++g2) {
            const int wr = (gp * 2 + g2) * HH + (real ? u : 0);
#pragma unroll
            for (int m = 0; m < 4; ++m) {
                const int j = lane * 4 + m * 256;   // <= 1023
#pragma unroll
                for (int q = 0; q < 4; ++q) {
                    wiv[g2][m][q] = real ? w_ih1[(size_t)wr * HH + j + q] : 0.0f;
                    whv[g2][m][q] = real ? w_hh1[(size_t)wr * HH + j + q] : 0.0f;
                }
            }
#pragma unroll
            for (int q = 0; q < 4; ++q) {
                const int j = 1024 + lane * 4 + q;
                const bool inb = real && lane < 8 && j < HH;
                wti[g2][q] = inb ? w_ih1[(size_t)wr * HH + j] : 0.0f;
                wth[g2][q] = inb ? w_hh1[(size_t)wr * HH + j] : 0.0f;
            }
            bs2[g2] = real ? (b_ih1[wr] + b_hh1[wr]) : 0.0f;
        }
#pragma unroll
        for (int g2 = 0; g2 < 2; ++g2)
#pragma unroll
            for (int m = 0; m < 4; ++m)
#pragma unroll
                for (int q = 0; q < 4; ++q) {
                    asm volatile("" : "+v"(wiv[g2][m][q]));
                    asm volatile("" : "+v"(whv[g2][m][q]));
                }
        const float bsl = 0.0f; (void)bsl;
        __syncthreads();

        long long budget = 20000000LL;
        float c_reg = 0.0f;                   // lives in wave0 lanes<8 (epilogue)
        for (int t = 0; t < TT; ++t) {
            // ---- phase P: epilogue(t-1) [wave0] || stage h2(t-1) [w4-11] || stage h1(t) [w12-15] ----
            if (w == 0) {
                if (t > 0) {
                    const float* gl = gbuf + ((t - 1) & 1) * 32;
                    if (lane < 8) {
                        const float gi = gl[lane], gf = gl[8 + lane];
                        const float gg = gl[16 + lane], go = gl[24 + lane];
                        const float iv = sigmf(gi), fv = sigmf(gf), gv = tanhf(gg), ov = sigmf(go);
                        c_reg = fv * c_reg + iv * gv;
                        float hv = ov * tanhf(c_reg);
                        if (wg * 8 + lane >= HH) hv = 0.0f;
                        st_u64(ring1 + (size_t)((t - 1) & R1M) * HSU + wg * 8 + lane,
                               pack((unsigned)t, hv));     // coalesced 64B burst
                        h2hist[(size_t)(t - 1) * HS + wg * 8 + lane] = hv;
                    }
                }
            } else if (w >= 4 && w < 12) {
                if (t > 0)
                    stage132w(ring1 + (size_t)((t - 1) & R1M) * HSU, bbuf + (t & 1) * UP,
                              (w - 4) * 132, lane, (unsigned)t, budget);
            } else if (w >= 12) {
                stage264w(ring0 + (size_t)(t & R0M) * HSU, abuf + (t & 1) * UP,
                          (w - 12) * 264, lane, (unsigned)(t + 1), budget);
            }
            __syncthreads();                   // A
            const float* ab = abuf + (t & 1) * UP;
            const float* bb = bbuf + (t & 1) * UP;
            float a0 = 0.0f, a1 = 0.0f;
#pragma unroll
            for (int m = 0; m < 4; ++m) {
                const float4 ha = *(const float4*)&ab[lane * 4 + m * 256];
                const float4 hc = *(const float4*)&bb[lane * 4 + m * 256];
                a0 = fmaf(wiv[0][m][0], ha.x, a0);
                a0 = fmaf(wiv[0][m][1], ha.y, a0);
                a0 = fmaf(wiv[0][m][2], ha.z, a0);
                a0 = fmaf(wiv[0][m][3], ha.w, a0);
                a0 = fmaf(whv[0][m][0], hc.x, a0);
                a0 = fmaf(whv[0][m][1], hc.y, a0);
                a0 = fmaf(whv[0][m][2], hc.z, a0);
                a0 = fmaf(whv[0][m][3], hc.w, a0);
                a1 = fmaf(wiv[1][m][0], ha.x, a1);
                a1 = fmaf(wiv[1][m][1], ha.y, a1);
                a1 = fmaf(wiv[1][m][2], ha.z, a1);
                a1 = fmaf(wiv[1][m][3], ha.w, a1);
                a1 = fmaf(whv[1][m][0], hc.x, a1);
                a1 = fmaf(whv[1][m][1], hc.y, a1);
                a1 = fmaf(whv[1][m][2], hc.z, a1);
                a1 = fmaf(whv[1][m][3], hc.w, a1);
            }
            if (lane < 8) {
                const float4 ha = *(const float4*)&ab[1024 + lane * 4];
                const float4 hc = *(const float4*)&bb[1024 + lane * 4];
                a0 = fmaf(wti[0][0], ha.x, a0);
                a0 = fmaf(wti[0][1], ha.y, a0);
                a0 = fmaf(wti[0][2], ha.z, a0);
                a0 = fmaf(wti[0][3], ha.w, a0);
                a0 = fmaf(wth[0][0], hc.x, a0);
                a0 = fmaf(wth[0][1], hc.y, a0);
                a0 = fmaf(wth[0][2], hc.z, a0);
                a0 = fmaf(wth[0][3], hc.w, a0);
                a1 = fmaf(wti[1][0], ha.x, a1);
                a1 = fmaf(wti[1][1], ha.y, a1);
                a1 = fmaf(wti[1][2], ha.z, a1);
                a1 = fmaf(wti[1][3], ha.w, a1);
                a1 = fmaf(wth[1][0], hc.x, a1);
                a1 = fmaf(wth[1][1], hc.y, a1);
                a1 = fmaf(wth[1][2], hc.z, a1);
                a1 = fmaf(wth[1][3], hc.w, a1);
            }
            // 64-lane butterflies
#pragma unroll
            for (int off = 1; off < 64; off <<= 1) {
                a0 += __shfl_xor(a0, off);
                a1 += __shfl_xor(a1, off);
            }
            if (lane == 0) {
                float* gw = gbuf + (t & 1) * 32;
                gw[(gp * 2 + 0) * 8 + du] = a0 + bs2[0];
                gw[(gp * 2 + 1) * 8 + du] = a1 + bs2[1];
            }
            __syncthreads();                   // B
            if (w == 1 && lane == 0 && wg == 0 && (t & 255) == 255)
                st_u32(l1prog, (unsigned)(t + 1));        // backpressure progress
        }
        // final epilogue for t = TT-1
        if (w == 0 && lane < 8) {
            const float* gl = gbuf + ((TT - 1) & 1) * 32;
            const float gi = gl[lane], gf = gl[8 + lane];
            const float gg = gl[16 + lane], go = gl[24 + lane];
            const float iv = sigmf(gi), fv = sigmf(gf), gv = tanhf(gg), ov = sigmf(go);
            c_reg = fv * c_reg + iv * gv;
            float hv = ov * tanhf(c_reg);
            if (wg * 8 + lane >= HH) hv = 0.0f;
            h2hist[(size_t)(TT - 1) * HS + wg * 8 + lane] = hv;
        }
    }
}

// ---------- final projection: out[t] = lin_w . h2[t] + lin_b ----------
__global__ __launch_bounds__(256) void wn_proj(
    const float* __restrict__ h2,
    const float* __restrict__ lin_w,
    const float* __restrict__ lin_b,
    float* __restrict__ out)
{
    const int lane = threadIdx.x & 63;
    const int wv   = threadIdx.x >> 6;
    const int t    = blockIdx.x * 4 + wv;
    const float* hp = h2 + (size_t)t * HS;
    float acc = 0.0f;
#pragma unroll
    for (int m = 0; m < 4; ++m) {
        const int j = lane * 4 + m * 256;        // covers [0,1024)
        const float4 h4 = *(const float4*)(hp + j);
        const float4 w4 = *(const float4*)(lin_w + j);
        acc += h4.x * w4.x + h4.y * w4.y + h4.z * w4.z + h4.w * w4.w;
    }
    if (lane == 0) {
#pragma unroll
        for (int j = 1024; j < HH; ++j) acc += hp[j] * lin_w[j];
    }
#pragma unroll
    for (int off = 1; off < 64; off <<= 1) acc += __shfl_xor(acc, off);
    if (lane == 0) out[t] = acc + lin_b[0];
}

extern "C" void kernel_launch(void* const* d_in, const int* in_sizes, int n_in,
                              void* d_out, int out_size, void* d_ws, size_t ws_size,
                              hipStream_t stream) {
    const float* x     = (const float*)d_in[0];
    const float* w_ih0 = (const float*)d_in[1];
    const float* w_hh0 = (const float*)d_in[2];
    const float* b_ih0 = (const float*)d_in[3];
    const float* b_hh0 = (const float*)d_in[4];
    const float* w_ih1 = (const float*)d_in[5];
    const float* w_hh1 = (const float*)d_in[6];
    const float* b_ih1 = (const float*)d_in[7];
    const float* b_hh1 = (const float*)d_in[8];
    const float* lin_w = (const float*)d_in[9];
    const float* lin_b = (const float*)d_in[10];
    float* out = (float*)d_out;

    char* ws = (char*)d_ws;
    const size_t R0B = (size_t)R0 * HSU * 8;        //  8,650,752
    const size_t R1B = (size_t)16 * HSU * 8;        //    135,168
    const size_t H2B = (size_t)TT * HS * 4;         // 69,206,016
    u64* ring0 = (u64*)(ws);
    u64* ring1 = (u64*)(ws + R0B);
    float* h2hist = (float*)(ws + R0B + R1B);
    unsigned* l1prog = (unsigned*)(ws + R0B + R1B + H2B);
    // No init kernel: 0xAA poison never matches any tag (1..16384), and the
    // poisoned l1prog reads as negative -> L0 throttles until L1 publishes.

    wn_fused<<<NWGT, 1024, 0, stream>>>(x, w_ih0, w_hh0, b_ih0, b_hh0,
                                        w_ih1, w_hh1, b_ih1, b_hh1,
                                        ring0, ring1, h2hist, l1prog);
    wn_proj<<<TT / 4, 256, 0, stream>>>(h2hist, lin_w, lin_b, out);
}